// Round 2
// baseline (42.354 us; speedup 1.0000x reference)
//
#include <hip/hip_runtime.h>

#define IMG 512
#define HW (IMG * IMG)      // 262144
#define NB 257              // bins (L = 512/2 + 1)
#define BATCH 16

// plane(h,w): h==0||w==0 -> 256; else 255 - min(h-1, w-1, 511-h, 511-w)
//           = 255 - min(m_h, d_w),  m_h = min(h-1,511-h), d_w = min(w-1,511-w)
// Row structure (h>=1): w=0 -> bin 256; d_w < m_h -> ramp bin 255-d_w (distinct
// per pixel within the row side); d_w >= m_h -> constant bin 255-m_h.

__global__ __launch_bounds__(256) void hist_kernel(const float* __restrict__ x,
                                                   float* __restrict__ prof) {
    const int b    = blockIdx.y;
    const int wid  = threadIdx.x >> 6;
    const int lane = threadIdx.x & 63;
    const int h    = (blockIdx.x << 2) + wid;   // one row per wave

    __shared__ float bins[NB];
    for (int i = threadIdx.x; i < NB; i += 256) bins[i] = 0.f;
    __syncthreads();

    const float* xr  = x + (size_t)b * 3 * HW + (size_t)h * IMG;
    const float* xg  = xr + HW;
    const float* xbl = xg + HW;

    const int m = min(h - 1, 511 - h);   // only meaningful for h >= 1
    float mid = 0.f;                     // sum of constant-bin (middle) pixels

#pragma unroll
    for (int j = 0; j < 2; ++j) {
        const int w0 = (((j << 6) + lane) << 2);          // 4 consecutive pixels
        const float4 r  = *reinterpret_cast<const float4*>(xr  + w0);
        const float4 g  = *reinterpret_cast<const float4*>(xg  + w0);
        const float4 bv = *reinterpret_cast<const float4*>(xbl + w0);

        float mg[4];
        mg[0] = 20.f * (0.299f * r.x + 0.587f * g.x + 0.114f * bv.x);
        mg[1] = 20.f * (0.299f * r.y + 0.587f * g.y + 0.114f * bv.y);
        mg[2] = 20.f * (0.299f * r.z + 0.587f * g.z + 0.114f * bv.z);
        mg[3] = 20.f * (0.299f * r.w + 0.587f * g.w + 0.114f * bv.w);

        if (h == 0) {
            // whole row is bin 256 -> all through the butterfly path
            mid += mg[0] + mg[1] + mg[2] + mg[3];
        } else {
#pragma unroll
            for (int t = 0; t < 4; ++t) {
                const int w = w0 + t;
                if (w == 0) {
                    atomicAdd(&bins[256], mg[t]);          // lane 0 only
                } else {
                    const int d = min(w - 1, 511 - w);
                    if (d >= m) mid += mg[t];              // constant middle bin
                    else        atomicAdd(&bins[255 - d], mg[t]); // distinct addrs
                }
            }
        }
    }

    // wave butterfly: middle-run sum -> one LDS atomic per wave
#pragma unroll
    for (int off = 32; off > 0; off >>= 1) mid += __shfl_down(mid, off, 64);
    if (lane == 0) atomicAdd(&bins[(h == 0) ? 256 : (255 - m)], mid);
    __syncthreads();

    float* pb = prof + (size_t)b * NB;
    for (int i = threadIdx.x; i < NB; i += 256) {
        const float v = bins[i];
        if (v != 0.f) atomicAdd(&pb[i], v);   // sparse flush, ~2(m+2) bins/block
    }
}

__global__ __launch_bounds__(256) void finalize_kernel(const float* __restrict__ prof,
                                                       const float* __restrict__ mask_n,
                                                       float* __restrict__ out) {
    __shared__ float smin[256];
    __shared__ float smax[256];
    float lmin = 3.402823466e+38f, lmax = -3.402823466e+38f;
    for (int i = threadIdx.x; i < BATCH * NB; i += 256) {
        const float v = prof[i] / mask_n[i % NB];
        lmin = fminf(lmin, v);
        lmax = fmaxf(lmax, v);
    }
    smin[threadIdx.x] = lmin;
    smax[threadIdx.x] = lmax;
    __syncthreads();
    for (int s = 128; s > 0; s >>= 1) {
        if (threadIdx.x < s) {
            smin[threadIdx.x] = fminf(smin[threadIdx.x], smin[threadIdx.x + s]);
            smax[threadIdx.x] = fmaxf(smax[threadIdx.x], smax[threadIdx.x + s]);
        }
        __syncthreads();
    }
    const float pmin = smin[0];
    const float inv = 1.f / (smax[0] - pmin);
    for (int i = threadIdx.x; i < BATCH * NB; i += 256) {
        const float v = prof[i] / mask_n[i % NB];
        out[i] = (v - pmin) * inv;
    }
}

extern "C" void kernel_launch(void* const* d_in, const int* in_sizes, int n_in,
                              void* d_out, int out_size, void* d_ws, size_t ws_size,
                              hipStream_t stream) {
    const float* x      = (const float*)d_in[0];   // [16,3,512,512] f32
    const float* mask_n = (const float*)d_in[2];   // [257] f32 (mask d_in[1] unused)
    float* out  = (float*)d_out;                   // [16,257] f32
    float* prof = (float*)d_ws;                    // [16,257] f32 accumulator

    hipMemsetAsync(prof, 0, (size_t)BATCH * NB * sizeof(float), stream);
    hist_kernel<<<dim3(128, BATCH), 256, 0, stream>>>(x, prof);
    finalize_kernel<<<1, 256, 0, stream>>>(prof, mask_n, out);
}